// Round 1
// 1023.156 us; speedup vs baseline: 1.1507x; 1.1507x over previous
//
#include <hip/hip_runtime.h>

// Problem dims
#define DM 32000   // vocab
#define DN 2048    // hidden
#define DD 1024    // embed dim
#define DB 2048    // batch
#define DKG 3072   // N + DIM

typedef __attribute__((ext_vector_type(4))) float floatx4;
typedef __attribute__((ext_vector_type(8))) short shortx8;

__device__ inline unsigned int f2bf(float f) {
    unsigned int u = __builtin_bit_cast(unsigned int, f);
    u += 0x7fffu + ((u >> 16) & 1u);   // round-to-nearest-even
    return u >> 16;
}

// packed f32x2 -> bf16x2 (RNE), 1 instr; no builtin on gfx950 (T12/m240)
__device__ inline unsigned int cvt_pk_bf16(float lo, float hi) {
    unsigned int r;
    asm("v_cvt_pk_bf16_f32 %0, %1, %2" : "=v"(r) : "v"(lo), "v"(hi));
    return r;
}

// async global->LDS, 16B per lane. dst must be wave-uniform; HW adds lane*16.
__device__ inline void gld_lds16(const void* g, void* l) {
    __builtin_amdgcn_global_load_lds(
        (const __attribute__((address_space(1))) unsigned int*)g,
        (__attribute__((address_space(3))) unsigned int*)l,
        16, 0, 0);
}

__device__ inline float fast_sigmoid(float x) { return 1.0f / (1.0f + __expf(-x)); }
__device__ inline float fast_tanh(float x) { return 1.0f - 2.0f / (__expf(2.0f * x) + 1.0f); }

// ---------------------------------------------------------------------------
// h_prev [N, B] f32  ->  z_t[b][k] bf16 for k in [0, 2048)   (64x64 LDS transpose)
// ---------------------------------------------------------------------------
__global__ __launch_bounds__(256) void transpose_h_kernel(
    const float* __restrict__ h_prev, unsigned short* __restrict__ z_t)
{
    __shared__ unsigned short T[64 * 66];
    int t = threadIdx.x;
    int b0 = blockIdx.x * 64, k0 = blockIdx.y * 64;
    int bi = t & 63, wv = t >> 6;
    #pragma unroll
    for (int i = 0; i < 16; i++) {
        int kl = wv + i * 4;
        float v = h_prev[(size_t)(k0 + kl) * DB + b0 + bi];
        T[kl * 66 + bi] = (unsigned short)f2bf(v);
    }
    __syncthreads();
    #pragma unroll
    for (int i = 0; i < 16; i++) {
        int r = wv + i * 4;
        z_t[(size_t)(b0 + r) * DKG + k0 + bi] = T[bi * 66 + r];
    }
}

// ---------------------------------------------------------------------------
// z_t[b][2048 + d] = bf16(emb[input_text[b]][d])  — one block per b
// ---------------------------------------------------------------------------
__global__ __launch_bounds__(256) void emb_gather_kernel(
    const int* __restrict__ idx, const float* __restrict__ emb,
    unsigned short* __restrict__ z_t)
{
    int b = blockIdx.x;
    int row = idx[b];
    int t = threadIdx.x;
    const floatx4 v = *(const floatx4*)(&emb[(size_t)row * DD + t * 4]);
    unsigned int p0 = (f2bf(v[1]) << 16) | f2bf(v[0]);
    unsigned int p1 = (f2bf(v[3]) << 16) | f2bf(v[2]);
    *(uint2*)(&z_t[(size_t)b * DKG + DN + t * 4]) = make_uint2(p0, p1);
}

// ---------------------------------------------------------------------------
// W_A f32 -> bf16 (RNE), 8 elems/thread, exact grid (no bounds check)
// ---------------------------------------------------------------------------
__global__ __launch_bounds__(256) void wconv_kernel(
    const float* __restrict__ src, unsigned short* __restrict__ dst)
{
    size_t i = ((size_t)blockIdx.x * 256 + threadIdx.x) * 8;
    floatx4 v0 = *(const floatx4*)(src + i);
    floatx4 v1 = *(const floatx4*)(src + i + 4);
    uint4 p;
    p.x = cvt_pk_bf16(v0[0], v0[1]);
    p.y = cvt_pk_bf16(v0[2], v0[3]);
    p.z = cvt_pk_bf16(v1[0], v1[1]);
    p.w = cvt_pk_bf16(v1[2], v1[3]);
    *(uint4*)(dst + i) = p;
}

// ---------------------------------------------------------------------------
// Shared GEMM geometry: 128x128 tile, BK=64, 4 waves (each 64x64), mfma 16x16x32.
// LDS tiles [128 rows][8 slots of 16B], XOR swizzle: phys_slot = logical ^ (row&7).
// global_load_lds writes LINEAR LDS; the swizzle is applied by permuting the
// GLOBAL source slot (involution), and the identical XOR on the ds_read side
// (rule #21: both-sides-or-neither). row&7 == lane&7 on the read side, so the
// 64-lane b128 read lands uniformly 8-deep per bank group (the b128 minimum).
// ---------------------------------------------------------------------------

// y-GEMM: A bf16 [Mrows, 2048] (pre-converted W_A half), Bt = h_t bf16 [2048,2048]
__global__ __launch_bounds__(256, 3) void gemm_wa_kernel(
    const unsigned short* __restrict__ A, const unsigned short* __restrict__ Bt,
    float* __restrict__ C, const float* __restrict__ bias)
{
    __shared__ unsigned short As[128 * 64];
    __shared__ unsigned short Bs[128 * 64];
    const int K = DN;
    int t = threadIdx.x;
    int lane = t & 63, wave = t >> 6;
    int wm = (wave >> 1) * 64, wn = (wave & 1) * 64;
    size_t m0 = (size_t)blockIdx.y * 128, n0 = (size_t)blockIdx.x * 128;
    int mrow = lane & 15, kgrp = lane >> 4, l7 = lane & 7;
    int r8 = t >> 3, lsl = t & 7;
    int ss = lsl ^ (r8 & 7);          // pre-swizzled source slot (const across i)

    floatx4 acc[4][4] = {};

    for (int k0 = 0; k0 < K; k0 += 64) {
        #pragma unroll
        for (int i = 0; i < 4; i++) {
            int row = i * 32 + r8;    // (i*256+t)>>3
            gld_lds16(A  + (m0 + row) * (size_t)K + k0 + ss * 8,
                      &As[(i * 256 + wave * 64) * 8]);
            gld_lds16(Bt + (n0 + row) * (size_t)K + k0 + ss * 8,
                      &Bs[(i * 256 + wave * 64) * 8]);
        }
        __syncthreads();              // compiler drains vmcnt before s_barrier
        #pragma unroll
        for (int ks = 0; ks < 2; ks++) {
            int so = ((ks * 4 + kgrp) ^ l7) * 8;   // swizzled read slot
            shortx8 af[4], bfv[4];
            #pragma unroll
            for (int mi = 0; mi < 4; mi++)
                af[mi] = *(const shortx8*)(&As[(wm + mi * 16 + mrow) * 64 + so]);
            #pragma unroll
            for (int ni = 0; ni < 4; ni++)
                bfv[ni] = *(const shortx8*)(&Bs[(wn + ni * 16 + mrow) * 64 + so]);
            #pragma unroll
            for (int mi = 0; mi < 4; mi++)
                #pragma unroll
                for (int ni = 0; ni < 4; ni++)
                    acc[mi][ni] = __builtin_amdgcn_mfma_f32_16x16x32_bf16(
                        af[mi], bfv[ni], acc[mi][ni], 0, 0, 0);
        }
        __syncthreads();
    }

    // epilogue: C/D layout col=lane&15, row=(lane>>4)*4+reg  [m89-verified]
    int cn = lane & 15, rb = kgrp * 4;
    #pragma unroll
    for (int mi = 0; mi < 4; mi++) {
        #pragma unroll
        for (int r = 0; r < 4; r++) {
            size_t row = m0 + wm + mi * 16 + rb + r;
            float bv = bias[row];
            #pragma unroll
            for (int ni = 0; ni < 4; ni++)
                C[row * DB + n0 + wn + ni * 16 + cn] = acc[mi][ni][r] + bv;
        }
    }
}

// gate GEMM: A f32 (weights, L3-resident) reg-staged with v_cvt_pk_bf16_f32
// into the swizzled LDS tile; B (z_t bf16) via global_load_lds. 4 gates on z.
__global__ __launch_bounds__(256, 3) void gemm_gates_kernel(
    const float* __restrict__ A0, const float* __restrict__ A1,
    const float* __restrict__ A2, const float* __restrict__ A3,
    const unsigned short* __restrict__ Bt,
    float* __restrict__ C0, float* __restrict__ C1,
    float* __restrict__ C2, float* __restrict__ C3)
{
    __shared__ unsigned short As[128 * 64];
    __shared__ unsigned short Bs[128 * 64];
    const int K = DKG;
    int t = threadIdx.x;
    int lane = t & 63, wave = t >> 6;
    int wm = (wave >> 1) * 64, wn = (wave & 1) * 64;
    int zz = blockIdx.z;
    const float* A = (zz == 0) ? A0 : (zz == 1) ? A1 : (zz == 2) ? A2 : A3;
    float* Cout    = (zz == 0) ? C0 : (zz == 1) ? C1 : (zz == 2) ? C2 : C3;
    size_t m0 = (size_t)blockIdx.y * 128, n0 = (size_t)blockIdx.x * 128;
    int mrow = lane & 15, kgrp = lane >> 4, l7 = lane & 7;
    int r8 = t >> 3, lsl = t & 7;
    int ss = lsl ^ (r8 & 7);

    floatx4 acc[4][4] = {};

    for (int k0 = 0; k0 < K; k0 += 64) {
        // B: async, pre-swizzled source
        #pragma unroll
        for (int i = 0; i < 4; i++) {
            int row = i * 32 + r8;
            gld_lds16(Bt + (n0 + row) * (size_t)K + k0 + ss * 8,
                      &Bs[(i * 256 + wave * 64) * 8]);
        }
        // A: f32 -> bf16 pack, swizzled ds_write (write side of the involution)
        #pragma unroll
        for (int i = 0; i < 4; i++) {
            int row = i * 32 + r8;
            const float* src = A + (m0 + row) * (size_t)K + k0 + lsl * 8;
            floatx4 v0 = *(const floatx4*)(src);
            floatx4 v1 = *(const floatx4*)(src + 4);
            uint4 p;
            p.x = cvt_pk_bf16(v0[0], v0[1]);
            p.y = cvt_pk_bf16(v0[2], v0[3]);
            p.z = cvt_pk_bf16(v1[0], v1[1]);
            p.w = cvt_pk_bf16(v1[2], v1[3]);
            *(uint4*)(&As[(row * 8 + ss) * 8]) = p;
        }
        __syncthreads();
        #pragma unroll
        for (int ks = 0; ks < 2; ks++) {
            int so = ((ks * 4 + kgrp) ^ l7) * 8;
            shortx8 af[4], bfv[4];
            #pragma unroll
            for (int mi = 0; mi < 4; mi++)
                af[mi] = *(const shortx8*)(&As[(wm + mi * 16 + mrow) * 64 + so]);
            #pragma unroll
            for (int ni = 0; ni < 4; ni++)
                bfv[ni] = *(const shortx8*)(&Bs[(wn + ni * 16 + mrow) * 64 + so]);
            #pragma unroll
            for (int mi = 0; mi < 4; mi++)
                #pragma unroll
                for (int ni = 0; ni < 4; ni++)
                    acc[mi][ni] = __builtin_amdgcn_mfma_f32_16x16x32_bf16(
                        af[mi], bfv[ni], acc[mi][ni], 0, 0, 0);
        }
        __syncthreads();
    }

    int cn = lane & 15, rb = kgrp * 4;
    #pragma unroll
    for (int mi = 0; mi < 4; mi++) {
        #pragma unroll
        for (int r = 0; r < 4; r++) {
            size_t row = m0 + wm + mi * 16 + rb + r;
            #pragma unroll
            for (int ni = 0; ni < 4; ni++)
                Cout[row * DB + n0 + wn + ni * 16 + cn] = acc[mi][ni][r];
        }
    }
}

// ---------------------------------------------------------------------------
// Gate math: f,i,o = sigmoid(P + b), tc = tanh(Pc + bC), C = f*Cp + i*tc,
// h = o*tanh(C). Writes C,h (f32, d_out) and h^T bf16 (ws) via LDS transpose.
// ---------------------------------------------------------------------------
__global__ __launch_bounds__(256) void pointwise_kernel(
    const float* __restrict__ Pf, const float* __restrict__ Pi,
    const float* __restrict__ Po, const float* __restrict__ Pc,
    const float* __restrict__ C_prev,
    const float* __restrict__ b_f, const float* __restrict__ b_i,
    const float* __restrict__ b_o, const float* __restrict__ b_C,
    float* __restrict__ outH, float* __restrict__ outC,
    unsigned short* __restrict__ h_t)
{
    __shared__ unsigned short T[64 * 66];
    int t = threadIdx.x;
    int b0 = blockIdx.x * 64, n0 = blockIdx.y * 64;
    int bi = t & 63, wv = t >> 6;
    #pragma unroll
    for (int i = 0; i < 16; i++) {
        int nl = wv + i * 4;
        size_t idx = (size_t)(n0 + nl) * DB + b0 + bi;
        float f  = fast_sigmoid(Pf[idx] + b_f[n0 + nl]);
        float ii = fast_sigmoid(Pi[idx] + b_i[n0 + nl]);
        float o  = fast_sigmoid(Po[idx] + b_o[n0 + nl]);
        float tc = fast_tanh(Pc[idx] + b_C[n0 + nl]);
        float C  = f * C_prev[idx] + ii * tc;
        float h  = o * fast_tanh(C);
        outC[idx] = C;
        outH[idx] = h;
        T[nl * 66 + bi] = (unsigned short)f2bf(h);
    }
    __syncthreads();
    #pragma unroll
    for (int i = 0; i < 16; i++) {
        int r = wv + i * 4;
        h_t[(size_t)(b0 + r) * DN + n0 + bi] = T[bi * 66 + r];
    }
}

// ---------------------------------------------------------------------------
extern "C" void kernel_launch(void* const* d_in, const int* in_sizes, int n_in,
                              void* d_out, int out_size, void* d_ws, size_t ws_size,
                              hipStream_t stream)
{
    const int*   input_text = (const int*)d_in[0];
    const float* h_prev = (const float*)d_in[1];
    const float* C_prev = (const float*)d_in[2];
    const float* emb    = (const float*)d_in[3];
    const float* W_A    = (const float*)d_in[4];
    const float* W_C    = (const float*)d_in[5];
    const float* W_f    = (const float*)d_in[6];
    const float* W_o    = (const float*)d_in[7];
    const float* W_i    = (const float*)d_in[8];
    const float* b_A    = (const float*)d_in[9];
    const float* b_C    = (const float*)d_in[10];
    const float* b_f    = (const float*)d_in[11];
    const float* b_o    = (const float*)d_in[12];
    const float* b_i    = (const float*)d_in[13];

    // workspace layout (88,080,384 bytes total, unchanged):
    //   [0,        12.58 MB)  z_t  (dead after gate GEMM)
    //   [12.58 MB, 79.69 MB)  Pf/Pi/Po/Pc (dead after pointwise)
    //   [79.69 MB, 88.08 MB)  h_t  (live through y-GEMMs)
    // wa (bf16 W_A half, 65.54 MB) ALIASES [0, 65.54 MB) — only written/read
    // after pointwise, when z_t and P are dead. Two halves, sequential.
    char* ws = (char*)d_ws;
    unsigned short* z_t = (unsigned short*)ws;                       // 2048*3072*2
    float* Pf = (float*)(ws + 12582912);                             // 4x 2048*2048*4
    float* Pi = (float*)(ws + 12582912 + 1 * 16777216);
    float* Po = (float*)(ws + 12582912 + 2 * 16777216);
    float* Pc = (float*)(ws + 12582912 + 3 * 16777216);
    unsigned short* h_t = (unsigned short*)(ws + 12582912 + 4 * 16777216); // 2048*2048*2
    unsigned short* wa  = (unsigned short*)ws;                       // 16000*2048*2 alias

    float* y    = (float*)d_out;                      // [32000, 2048]
    float* outH = y + (size_t)DM * DB;                // [2048, 2048]
    float* outC = outH + (size_t)DN * DB;             // [2048, 2048]

    // 1. z^T build: h part (transpose) + emb part (gather)
    transpose_h_kernel<<<dim3(32, 32), 256, 0, stream>>>(h_prev, z_t);
    emb_gather_kernel<<<dim3(2048), 256, 0, stream>>>(input_text, emb, z_t);

    // 2. fused 4-gate GEMM: P_g = W_g @ z   (grid.z = gate)
    gemm_gates_kernel<<<dim3(16, 16, 4), 256, 0, stream>>>(
        W_f, W_i, W_o, W_C, z_t, Pf, Pi, Po, Pc);

    // 3. gates -> C, h, h^T
    pointwise_kernel<<<dim3(32, 32), 256, 0, stream>>>(
        Pf, Pi, Po, Pc, C_prev, b_f, b_i, b_o, b_C, outH, outC, h_t);

    // 4. y = W_A @ h + b_A, in two M-halves: convert W_A half -> bf16 (aliased
    //    scratch), then bf16 GEMM on it. 16000 rows per half (125 tile rows).
    wconv_kernel<<<dim3(16000), 256, 0, stream>>>(W_A, wa);
    gemm_wa_kernel<<<dim3(16, 125), 256, 0, stream>>>(wa, h_t, y, b_A);
    wconv_kernel<<<dim3(16000), 256, 0, stream>>>(W_A + (size_t)16000 * DN, wa);
    gemm_wa_kernel<<<dim3(16, 125), 256, 0, stream>>>(
        wa, h_t, y + (size_t)16000 * DB, b_A + 16000);
}

// Round 2
// 979.310 us; speedup vs baseline: 1.2022x; 1.0448x over previous
//
#include <hip/hip_runtime.h>

// Problem dims
#define DM 32000   // vocab
#define DN 2048    // hidden
#define DD 1024    // embed dim
#define DB 2048    // batch
#define DKG 3072   // N + DIM

typedef __attribute__((ext_vector_type(4))) float floatx4;
typedef __attribute__((ext_vector_type(8))) short shortx8;

__device__ inline unsigned int f2bf(float f) {
    unsigned int u = __builtin_bit_cast(unsigned int, f);
    u += 0x7fffu + ((u >> 16) & 1u);   // round-to-nearest-even
    return u >> 16;
}

// packed f32x2 -> bf16x2 (RNE), 1 instr; no builtin on gfx950 (T12/m240)
__device__ inline unsigned int cvt_pk_bf16(float lo, float hi) {
    unsigned int r;
    asm("v_cvt_pk_bf16_f32 %0, %1, %2" : "=v"(r) : "v"(lo), "v"(hi));
    return r;
}

// async global->LDS, 16B per lane. dst must be wave-uniform; HW adds lane*16.
__device__ inline void gld_lds16(const void* g, void* l) {
    __builtin_amdgcn_global_load_lds(
        (const __attribute__((address_space(1))) unsigned int*)g,
        (__attribute__((address_space(3))) unsigned int*)l,
        16, 0, 0);
}

__device__ inline float fast_sigmoid(float x) { return 1.0f / (1.0f + __expf(-x)); }
__device__ inline float fast_tanh(float x) { return 1.0f - 2.0f / (__expf(2.0f * x) + 1.0f); }

// ---------------------------------------------------------------------------
// h_prev [N, B] f32  ->  z_t[b][k] bf16 for k in [0, 2048)   (64x64 LDS transpose)
// ---------------------------------------------------------------------------
__global__ __launch_bounds__(256) void transpose_h_kernel(
    const float* __restrict__ h_prev, unsigned short* __restrict__ z_t)
{
    __shared__ unsigned short T[64 * 66];
    int t = threadIdx.x;
    int b0 = blockIdx.x * 64, k0 = blockIdx.y * 64;
    int bi = t & 63, wv = t >> 6;
    #pragma unroll
    for (int i = 0; i < 16; i++) {
        int kl = wv + i * 4;
        float v = h_prev[(size_t)(k0 + kl) * DB + b0 + bi];
        T[kl * 66 + bi] = (unsigned short)f2bf(v);
    }
    __syncthreads();
    #pragma unroll
    for (int i = 0; i < 16; i++) {
        int r = wv + i * 4;
        z_t[(size_t)(b0 + r) * DKG + k0 + bi] = T[bi * 66 + r];
    }
}

// ---------------------------------------------------------------------------
// z_t[b][2048 + d] = bf16(emb[input_text[b]][d])  — one block per b
// ---------------------------------------------------------------------------
__global__ __launch_bounds__(256) void emb_gather_kernel(
    const int* __restrict__ idx, const float* __restrict__ emb,
    unsigned short* __restrict__ z_t)
{
    int b = blockIdx.x;
    int row = idx[b];
    int t = threadIdx.x;
    const floatx4 v = *(const floatx4*)(&emb[(size_t)row * DD + t * 4]);
    unsigned int p0 = (f2bf(v[1]) << 16) | f2bf(v[0]);
    unsigned int p1 = (f2bf(v[3]) << 16) | f2bf(v[2]);
    *(uint2*)(&z_t[(size_t)b * DKG + DN + t * 4]) = make_uint2(p0, p1);
}

// ---------------------------------------------------------------------------
// f32 -> bf16 (RNE) stream convert, 8 elems/thread, exact grid
// ---------------------------------------------------------------------------
__global__ __launch_bounds__(256) void wconv_kernel(
    const float* __restrict__ src, unsigned short* __restrict__ dst)
{
    size_t i = ((size_t)blockIdx.x * 256 + threadIdx.x) * 8;
    floatx4 v0 = *(const floatx4*)(src + i);
    floatx4 v1 = *(const floatx4*)(src + i + 4);
    uint4 p;
    p.x = cvt_pk_bf16(v0[0], v0[1]);
    p.y = cvt_pk_bf16(v0[2], v0[3]);
    p.z = cvt_pk_bf16(v1[0], v1[1]);
    p.w = cvt_pk_bf16(v1[2], v1[3]);
    *(uint4*)(dst + i) = p;
}

// ---------------------------------------------------------------------------
// Pure-bf16 GEMM: C[m][b] = A[m][:] . Bt[b][:] (+bias[m] if bias != null).
// 128x128 tile, BK=64, 4 waves (64x64 each), mfma_f32_16x16x32_bf16.
// Both operands staged with global_load_lds (width 16). LDS tiles
// [128 rows][8 slots of 16B]; XOR swizzle phys_slot = logical ^ (row&7),
// applied on the GLOBAL source slot (involution) and on the ds_read side
// (rule #21). 64-lane b128 reads land uniformly 8-deep per bank span.
// T1: XCD-aware block swizzle (grid.x*grid.y % 8 == 0 for all launches);
// each XCD gets a contiguous chunk of M-tiles -> A-panels hit its L2.
// ---------------------------------------------------------------------------
__global__ __launch_bounds__(256, 3) void gemm_bt16_kernel(
    const unsigned short* __restrict__ A, const unsigned short* __restrict__ Bt,
    float* __restrict__ C, const float* __restrict__ bias, int K)
{
    __shared__ unsigned short As[128 * 64];
    __shared__ unsigned short Bs[128 * 64];
    int t = threadIdx.x;
    int lane = t & 63, wave = t >> 6;
    int wm = (wave >> 1) * 64, wn = (wave & 1) * 64;

    // T1 XCD swizzle (bijective: nwg % 8 == 0; gridDim.x == 16 always here)
    int nwg = gridDim.x * gridDim.y;
    int flat = blockIdx.y * gridDim.x + blockIdx.x;
    int swz = (flat & 7) * (nwg >> 3) + (flat >> 3);
    size_t m0 = (size_t)(swz >> 4) * 128, n0 = (size_t)(swz & 15) * 128;

    int mrow = lane & 15, kgrp = lane >> 4, l7 = lane & 7;
    int r8 = t >> 3, lsl = t & 7;
    int ss = lsl ^ (r8 & 7);          // pre-swizzled source slot

    floatx4 acc[4][4] = {};

    for (int k0 = 0; k0 < K; k0 += 64) {
        #pragma unroll
        for (int i = 0; i < 4; i++) {
            int row = i * 32 + r8;    // (i*256+t)>>3
            gld_lds16(A  + (m0 + row) * (size_t)K + k0 + ss * 8,
                      &As[(i * 256 + wave * 64) * 8]);
            gld_lds16(Bt + (n0 + row) * (size_t)K + k0 + ss * 8,
                      &Bs[(i * 256 + wave * 64) * 8]);
        }
        __syncthreads();              // compiler drains vmcnt before s_barrier
        #pragma unroll
        for (int ks = 0; ks < 2; ks++) {
            int so = ((ks * 4 + kgrp) ^ l7) * 8;   // swizzled read slot
            shortx8 af[4], bfv[4];
            #pragma unroll
            for (int mi = 0; mi < 4; mi++)
                af[mi] = *(const shortx8*)(&As[(wm + mi * 16 + mrow) * 64 + so]);
            #pragma unroll
            for (int ni = 0; ni < 4; ni++)
                bfv[ni] = *(const shortx8*)(&Bs[(wn + ni * 16 + mrow) * 64 + so]);
            #pragma unroll
            for (int mi = 0; mi < 4; mi++)
                #pragma unroll
                for (int ni = 0; ni < 4; ni++)
                    acc[mi][ni] = __builtin_amdgcn_mfma_f32_16x16x32_bf16(
                        af[mi], bfv[ni], acc[mi][ni], 0, 0, 0);
        }
        __syncthreads();
    }

    // epilogue: C/D layout col=lane&15, row=(lane>>4)*4+reg  [m89-verified]
    int cn = lane & 15, rb = kgrp * 4;
    #pragma unroll
    for (int mi = 0; mi < 4; mi++) {
        #pragma unroll
        for (int r = 0; r < 4; r++) {
            size_t row = m0 + wm + mi * 16 + rb + r;
            float bv = bias ? bias[row] : 0.0f;
            #pragma unroll
            for (int ni = 0; ni < 4; ni++)
                C[row * DB + n0 + wn + ni * 16 + cn] = acc[mi][ni][r] + bv;
        }
    }
}

// ---------------------------------------------------------------------------
// Gate math: f,i,o = sigmoid(P + b), tc = tanh(Pc + bC), C = f*Cp + i*tc,
// h = o*tanh(C). Writes C,h (f32, d_out) and h^T bf16 (ws) via LDS transpose.
// ---------------------------------------------------------------------------
__global__ __launch_bounds__(256) void pointwise_kernel(
    const float* __restrict__ Pf, const float* __restrict__ Pi,
    const float* __restrict__ Po, const float* __restrict__ Pc,
    const float* __restrict__ C_prev,
    const float* __restrict__ b_f, const float* __restrict__ b_i,
    const float* __restrict__ b_o, const float* __restrict__ b_C,
    float* __restrict__ outH, float* __restrict__ outC,
    unsigned short* __restrict__ h_t)
{
    __shared__ unsigned short T[64 * 66];
    int t = threadIdx.x;
    int b0 = blockIdx.x * 64, n0 = blockIdx.y * 64;
    int bi = t & 63, wv = t >> 6;
    #pragma unroll
    for (int i = 0; i < 16; i++) {
        int nl = wv + i * 4;
        size_t idx = (size_t)(n0 + nl) * DB + b0 + bi;
        float f  = fast_sigmoid(Pf[idx] + b_f[n0 + nl]);
        float ii = fast_sigmoid(Pi[idx] + b_i[n0 + nl]);
        float o  = fast_sigmoid(Po[idx] + b_o[n0 + nl]);
        float tc = fast_tanh(Pc[idx] + b_C[n0 + nl]);
        float C  = f * C_prev[idx] + ii * tc;
        float h  = o * fast_tanh(C);
        outC[idx] = C;
        outH[idx] = h;
        T[nl * 66 + bi] = (unsigned short)f2bf(h);
    }
    __syncthreads();
    #pragma unroll
    for (int i = 0; i < 16; i++) {
        int r = wv + i * 4;
        h_t[(size_t)(b0 + r) * DN + n0 + bi] = T[bi * 66 + r];
    }
}

// ---------------------------------------------------------------------------
extern "C" void kernel_launch(void* const* d_in, const int* in_sizes, int n_in,
                              void* d_out, int out_size, void* d_ws, size_t ws_size,
                              hipStream_t stream)
{
    const int*   input_text = (const int*)d_in[0];
    const float* h_prev = (const float*)d_in[1];
    const float* C_prev = (const float*)d_in[2];
    const float* emb    = (const float*)d_in[3];
    const float* W_A    = (const float*)d_in[4];
    const float* W_C    = (const float*)d_in[5];
    const float* W_f    = (const float*)d_in[6];
    const float* W_o    = (const float*)d_in[7];
    const float* W_i    = (const float*)d_in[8];
    const float* b_A    = (const float*)d_in[9];
    const float* b_C    = (const float*)d_in[10];
    const float* b_f    = (const float*)d_in[11];
    const float* b_o    = (const float*)d_in[12];
    const float* b_i    = (const float*)d_in[13];

    // workspace layout (88,080,384 bytes total, unchanged):
    //   [0,        12.58 MB)  z_t  (dead after gate GEMM)
    //   [12.58 MB, 79.69 MB)  P = Pf|Pi|Po|Pc contiguous (dead after pointwise)
    //   [79.69 MB, 88.08 MB)  h_t  (live through y-GEMMs)
    // wa (bf16 W_A half, 65.54 MB) aliases [0, 65.54 MB) — used after pointwise.
    char* ws = (char*)d_ws;
    unsigned short* z_t = (unsigned short*)ws;                       // 2048*3072*2
    float* P  = (float*)(ws + 12582912);                             // 8192 x 2048 f32
    float* Pf = P;
    float* Pi = (float*)(ws + 12582912 + 1 * 16777216);
    float* Po = (float*)(ws + 12582912 + 2 * 16777216);
    float* Pc = (float*)(ws + 12582912 + 3 * 16777216);
    unsigned short* h_t = (unsigned short*)(ws + 12582912 + 4 * 16777216); // 2048*2048*2
    unsigned short* wa  = (unsigned short*)ws;                       // 16000*2048*2 alias

    float* y    = (float*)d_out;                      // [32000, 2048]
    float* outH = y + (size_t)DM * DB;                // [2048, 2048]
    float* outC = outH + (size_t)DN * DB;             // [2048, 2048]

    // Gate weights bf16 [8192, 3072], scratch inside y (dead until step 4).
    // Row order matches P order: f, i, o, C.
    unsigned short* wg = (unsigned short*)y;          // 50.3 MB < 262 MB

    // 0. convert gate weights to bf16 (order f, i, o, C)
    const size_t WGN = (size_t)DN * DKG;              // 6,291,456 elems per gate
    wconv_kernel<<<dim3(3072), 256, 0, stream>>>(W_f, wg + 0 * WGN);
    wconv_kernel<<<dim3(3072), 256, 0, stream>>>(W_i, wg + 1 * WGN);
    wconv_kernel<<<dim3(3072), 256, 0, stream>>>(W_o, wg + 2 * WGN);
    wconv_kernel<<<dim3(3072), 256, 0, stream>>>(W_C, wg + 3 * WGN);

    // 1. z^T build: h part (transpose) + emb part (gather)
    transpose_h_kernel<<<dim3(32, 32), 256, 0, stream>>>(h_prev, z_t);
    emb_gather_kernel<<<dim3(2048), 256, 0, stream>>>(input_text, emb, z_t);

    // 2. merged 4-gate GEMM: P = Wg(bf16) @ z, M=8192, K=3072
    gemm_bt16_kernel<<<dim3(16, 64), 256, 0, stream>>>(
        wg, z_t, P, nullptr, DKG);

    // 3. gates -> C, h, h^T
    pointwise_kernel<<<dim3(32, 32), 256, 0, stream>>>(
        Pf, Pi, Po, Pc, C_prev, b_f, b_i, b_o, b_C, outH, outC, h_t);

    // 4. y = W_A @ h + b_A, in two M-halves: convert W_A half -> bf16 (aliased
    //    ws scratch, z_t/P dead), then bf16 GEMM. 16000 rows = 125 tile rows.
    wconv_kernel<<<dim3(16000), 256, 0, stream>>>(W_A, wa);
    gemm_bt16_kernel<<<dim3(16, 125), 256, 0, stream>>>(wa, h_t, y, b_A, DN);
    wconv_kernel<<<dim3(16000), 256, 0, stream>>>(W_A + (size_t)16000 * DN, wa);
    gemm_bt16_kernel<<<dim3(16, 125), 256, 0, stream>>>(
        wa, h_t, y + (size_t)16000 * DB, b_A + 16000, DN);
}